// Round 3
// baseline (817.366 us; speedup 1.0000x reference)
//
#include <hip/hip_runtime.h>

#define N_NODES 40000
#define N_EDGES 640000

typedef __attribute__((ext_vector_type(8))) short short8;
typedef __attribute__((ext_vector_type(4))) float float4v;

__device__ inline short f2bf(float f) {
  unsigned u = __float_as_uint(f);
  unsigned r = (u + 0x7FFFu + ((u >> 16) & 1u)) >> 16;
  return (short)r;
}
__device__ inline float bf_lo(unsigned u) { return __uint_as_float(u << 16); }
__device__ inline float bf_hi(unsigned u) { return __uint_as_float(u & 0xFFFF0000u); }

// ---- convert + transpose weights to bf16: Wt[c][k] = bf16(W[k][c]) ----
__global__ void prep_w(const float* __restrict__ Wm, const float* __restrict__ We,
                       const float* __restrict__ Ws, short* __restrict__ WtM,
                       short* __restrict__ WtE, short* __restrict__ WtS) {
  int i = blockIdx.x * 256 + threadIdx.x;  // 40960 total
  if (i < 16384) {
    int c = i >> 7, k = i & 127;
    WtM[c * 128 + k] = f2bf(Wm[k * 128 + c]);
  } else if (i < 32768) {
    int j = i - 16384;
    int c = j >> 7, k = j & 127;
    WtE[c * 128 + k] = f2bf(We[k * 128 + c]);
  } else {
    int j = i - 32768;
    int c = j >> 7, k = j & 127;  // c in 0..63
    WtS[c * 128 + k] = f2bf(Ws[k * 64 + c]);
  }
}

// ---- generic row-tile GEMM: out[M, NT*16] = A[M,128] @ W[128, NT*16] + bias ----
template <int NT>
__global__ __launch_bounds__(256) void gemm_rows(const float* __restrict__ A,
                                                 const short* __restrict__ Wt,
                                                 const float* __restrict__ bias,
                                                 float* __restrict__ out) {
  __shared__ short wt[NT * 16 * 136];
  for (int i = threadIdx.x; i < NT * 16 * 16; i += 256) {
    int c = i >> 4, j = i & 15;
    *(uint4*)&wt[c * 136 + j * 8] = ((const uint4*)Wt)[i];
  }
  __syncthreads();
  const int l = threadIdx.x & 63, w = threadIdx.x >> 6;
  const int lr = l & 15, q = l >> 4;
  const int row = blockIdx.x * 64 + w * 16 + lr;
  float4v acc[NT];
#pragma unroll
  for (int t = 0; t < NT; ++t) acc[t] = (float4v){0.f, 0.f, 0.f, 0.f};
  const float* ap = A + (size_t)row * 128 + q * 8;
#pragma unroll
  for (int s = 0; s < 4; ++s) {
    float4 a0 = *(const float4*)(ap + s * 32);
    float4 a1 = *(const float4*)(ap + s * 32 + 4);
    short8 af;
    af[0] = f2bf(a0.x); af[1] = f2bf(a0.y); af[2] = f2bf(a0.z); af[3] = f2bf(a0.w);
    af[4] = f2bf(a1.x); af[5] = f2bf(a1.y); af[6] = f2bf(a1.z); af[7] = f2bf(a1.w);
#pragma unroll
    for (int t = 0; t < NT; ++t) {
      short8 bf = *(const short8*)&wt[(t * 16 + lr) * 136 + s * 32 + q * 8];
      acc[t] = __builtin_amdgcn_mfma_f32_16x16x32_bf16(af, bf, acc[t], 0, 0, 0);
    }
  }
  const int orow = blockIdx.x * 64 + w * 16 + q * 4;
#pragma unroll
  for (int t = 0; t < NT; ++t) {
    int col = lr + 16 * t;
    float b = bias[col];
#pragma unroll
    for (int j = 0; j < 4; ++j)
      out[(size_t)(orow + j) * (NT * 16) + col] = acc[t][j] + b;
  }
}

// ==================== CSR build (by destination) ====================

__global__ void hist_k(const int* __restrict__ dst, int* __restrict__ cnt,
                       int* __restrict__ rank) {
  int e = blockIdx.x * 256 + threadIdx.x;  // E exact
  rank[e] = atomicAdd(&cnt[dst[e]], 1);
}

// single-block exclusive scan of cnt[0..N) -> ofs[0..N]
__global__ __launch_bounds__(1024) void scan_k(const int* __restrict__ cnt,
                                               int* __restrict__ ofs) {
  __shared__ int tsum[1024];
  const int t = threadIdx.x;
  const int b = t * 40;                       // 1024*40 = 40960 >= 40000
  const int hi = min(b + 40, N_NODES);
  int s = 0;
  for (int i = b; i < hi; ++i) s += cnt[i];
  tsum[t] = s;
  __syncthreads();
  for (int d = 1; d < 1024; d <<= 1) {
    int v = (t >= d) ? tsum[t - d] : 0;
    __syncthreads();
    tsum[t] += v;
    __syncthreads();
  }
  int run = (t == 0) ? 0 : tsum[t - 1];       // exclusive base for this chunk
  for (int i = b; i < hi; ++i) { ofs[i] = run; run += cnt[i]; }
  if (t == 1023) ofs[N_NODES] = run;          // grand total (chunks >=1000 empty)
}

// pos[e] = CSR slot of edge e
__global__ void pos_k(const int* __restrict__ dst, const int* __restrict__ ofs,
                      const int* __restrict__ rank, int* __restrict__ pos) {
  int e = blockIdx.x * 256 + threadIdx.x;  // E exact
  pos[e] = ofs[dst[e]] + rank[e];
}

// ---- fused edge kernel: le = ea@W_edge + b_edge (store, edge order),
//      m = le + xm[src]; w_h = exp(leaky(sum_c m_h*att_h)) -> wcsr[pos];
//      m packed bf16 head-pairs -> mcsr[pos] (CSR order, 256 B/row) ----
__global__ __launch_bounds__(256) void edge_kernel(
    const float* __restrict__ ea, const short* __restrict__ WtE,
    const float* __restrict__ b_edge, const float* __restrict__ xm,
    const float* __restrict__ att, const int* __restrict__ src,
    const int* __restrict__ pos, float* __restrict__ le_out,
    float* __restrict__ wcsr, unsigned* __restrict__ mcsr) {
  __shared__ short wt[128 * 136];            // 34816 B; reused as m-stage after MFMA
  __shared__ int sid[64];
  __shared__ int pid[64];
  unsigned* mst = (unsigned*)wt;             // [64 rows][stride 72] u32 head-pairs
  for (int i = threadIdx.x; i < 128 * 16; i += 256) {
    int c = i >> 4, j = i & 15;
    *(uint4*)&wt[c * 136 + j * 8] = ((const uint4*)WtE)[i];
  }
  if (threadIdx.x < 64) {
    sid[threadIdx.x] = src[blockIdx.x * 64 + threadIdx.x];
    pid[threadIdx.x] = pos[blockIdx.x * 64 + threadIdx.x];
  }
  __syncthreads();
  const int l = threadIdx.x & 63, w = threadIdx.x >> 6;
  const int lr = l & 15, q = l >> 4;
  const int r0 = blockIdx.x * 64 + w * 16;
  float4v acc[8];
#pragma unroll
  for (int t = 0; t < 8; ++t) acc[t] = (float4v){0.f, 0.f, 0.f, 0.f};
  const float* ap = ea + (size_t)(r0 + lr) * 128 + q * 8;
#pragma unroll
  for (int s = 0; s < 4; ++s) {
    float4 a0 = *(const float4*)(ap + s * 32);
    float4 a1 = *(const float4*)(ap + s * 32 + 4);
    short8 af;
    af[0] = f2bf(a0.x); af[1] = f2bf(a0.y); af[2] = f2bf(a0.z); af[3] = f2bf(a0.w);
    af[4] = f2bf(a1.x); af[5] = f2bf(a1.y); af[6] = f2bf(a1.z); af[7] = f2bf(a1.w);
#pragma unroll
    for (int t = 0; t < 8; ++t) {
      short8 bf = *(const short8*)&wt[(t * 16 + lr) * 136 + s * 32 + q * 8];
      acc[t] = __builtin_amdgcn_mfma_f32_16x16x32_bf16(af, bf, acc[t], 0, 0, 0);
    }
  }
  __syncthreads();  // all wt reads done before mst overwrite (aliased LDS)
  const int rb = q * 4;
  int sidr[4];
#pragma unroll
  for (int j = 0; j < 4; ++j) sidr[j] = sid[w * 16 + rb + j];
  float p[8];
#pragma unroll
  for (int k = 0; k < 8; ++k) p[k] = 0.f;
  float mv0[4][4];  // head-0 m values, kept for pairing with head 1
#pragma unroll
  for (int t = 0; t < 8; ++t) {
    int col = lr + 16 * t;
    float b = b_edge[col];
    float av = att[col];
    int hp = (t >> 2) * 4;  // head = col>>6 = t>>2
#pragma unroll
    for (int j = 0; j < 4; ++j) {
      float lev = acc[t][j] + b;
      le_out[(size_t)(r0 + rb + j) * 128 + col] = lev;
      float mv = lev + xm[(size_t)sidr[j] * 128 + col];
      p[hp + j] += mv * av;
      if (t < 4) {
        mv0[t][j] = mv;
      } else {
        unsigned u = (unsigned)(unsigned short)f2bf(mv0[t - 4][j]) |
                     ((unsigned)(unsigned short)f2bf(mv) << 16);
        mst[(w * 16 + rb + j) * 72 + lr + 16 * (t - 4)] = u;
      }
    }
  }
  // butterfly-reduce over the 16 lanes of each quad group
#pragma unroll
  for (int d = 1; d < 16; d <<= 1) {
#pragma unroll
    for (int k = 0; k < 8; ++k) p[k] += __shfl_xor(p[k], d);
  }
  if (lr < 8) {
    int j = lr >> 1, h = lr & 1;
    float v = p[h * 4 + j];
    float lk = v > 0.f ? v : 0.2f * v;
    wcsr[(size_t)pid[w * 16 + rb + j] * 2 + h] = __expf(lk);
  }
  __syncthreads();  // mst fully written
  // copy out: 4 threads per row, 64 B each (row = 256 B contiguous at CSR slot)
  {
    const int row = threadIdx.x >> 2, part = threadIdx.x & 3;
    const unsigned* sp = &mst[row * 72 + part * 16];
    uint4* dp = (uint4*)(mcsr + (size_t)pid[row] * 64 + part * 16);
#pragma unroll
    for (int k = 0; k < 4; ++k) dp[k] = ((const uint4*)sp)[k];
  }
}

// ==================== per-node softmax + aggregation: pure streaming ====================
// one wave per node; lane l owns channel l. Edges of node n are rows [ofs[n],ofs[n+1])
// of mcsr (u32 head-pair per channel) with matching wcsr weights. Single fused pass:
// unnormalized per-head accumulators + denominators, one divide at the end.
__global__ __launch_bounds__(256) void node_agg(
    const unsigned* __restrict__ mcsr, const float* __restrict__ wcsr,
    const float* __restrict__ xs, const int* __restrict__ ofs,
    float* __restrict__ out) {
  const int w = threadIdx.x >> 6, l = threadIdx.x & 63;
  const int n = blockIdx.x * 4 + w;  // grid 10000 -> 40000 nodes exact
  const int beg = ofs[n];
  const int deg = ofs[n + 1] - beg;
  float acc0 = 0.f, acc1 = 0.f, den0 = 0.f, den1 = 0.f;
  const unsigned* mp = mcsr + (size_t)beg * 64 + l;
  const float* wp = wcsr + (size_t)beg * 2;
  int i = 0;
  for (; i + 4 <= deg; i += 4) {
    unsigned u0 = mp[0], u1 = mp[64], u2 = mp[128], u3 = mp[192];
    float wa0 = wp[0], wb0 = wp[1];
    float wa1 = wp[2], wb1 = wp[3];
    float wa2 = wp[4], wb2 = wp[5];
    float wa3 = wp[6], wb3 = wp[7];
    acc0 += wa0 * bf_lo(u0) + wa1 * bf_lo(u1) + wa2 * bf_lo(u2) + wa3 * bf_lo(u3);
    acc1 += wb0 * bf_hi(u0) + wb1 * bf_hi(u1) + wb2 * bf_hi(u2) + wb3 * bf_hi(u3);
    den0 += wa0 + wa1 + wa2 + wa3;
    den1 += wb0 + wb1 + wb2 + wb3;
    mp += 256;
    wp += 8;
  }
  for (; i < deg; ++i) {
    unsigned u = mp[0];
    float wa = wp[0], wb = wp[1];
    acc0 += wa * bf_lo(u);
    acc1 += wb * bf_hi(u);
    den0 += wa;
    den1 += wb;
    mp += 64;
    wp += 2;
  }
  float r0 = 1.f / (den0 + 1e-16f);
  float r1 = 1.f / (den1 + 1e-16f);
  out[(size_t)n * 64 + l] = 0.5f * (acc0 * r0 + acc1 * r1) + xs[(size_t)n * 64 + l];
}

extern "C" void kernel_launch(void* const* d_in, const int* in_sizes, int n_in,
                              void* d_out, int out_size, void* d_ws, size_t ws_size,
                              hipStream_t stream) {
  const float* x      = (const float*)d_in[0];
  const float* ea     = (const float*)d_in[1];
  const float* W_msg  = (const float*)d_in[2];
  const float* b_msg  = (const float*)d_in[3];
  const float* W_edge = (const float*)d_in[4];
  const float* b_edge = (const float*)d_in[5];
  const float* W_self = (const float*)d_in[6];
  const float* b_self = (const float*)d_in[7];
  const float* att    = (const float*)d_in[8];
  const int*   eidx   = (const int*)d_in[9];
  const int* src = eidx;
  const int* dst = eidx + N_EDGES;
  float* out_p = (float*)d_out;
  float* le_p  = out_p + (size_t)N_NODES * 64;

  char* ws = (char*)d_ws;
  short* WtM   = (short*)(ws);                 // 32,768 B
  short* WtE   = (short*)(ws + 32768);         // 32,768 B
  short* WtS   = (short*)(ws + 65536);         // 16,384 B
  float* xm    = (float*)(ws + 81920);         // N*128*4 =  20,480,000 B
  float* xs    = (float*)(ws + 20561920);      // N*64*4  =  10,240,000 B
  float* wcsr  = (float*)(ws + 30801920);      // E*2*4   =   5,120,000 B
  int*   cnt   = (int*)(ws + 35921920);        // N*4     =     160,000 B
  int*   ofs   = (int*)(ws + 36081920);        // (N+1)*4 =     160,016 B (pad)
  int*   rank  = (int*)(ws + 36241936);        // E*4     =   2,560,000 B
  int*   pos   = (int*)(ws + 38801936);        // E*4     =   2,560,000 B
  unsigned* mcsr = (unsigned*)(ws + 41361936); // E*64*4  = 163,840,000 B
  // total 205,201,936 B

  // zero only the histogram counters
  hipMemsetAsync(cnt, 0, 160000, stream);

  prep_w<<<160, 256, 0, stream>>>(W_msg, W_edge, W_self, WtM, WtE, WtS);
  gemm_rows<8><<<625, 256, 0, stream>>>(x, WtM, b_msg, xm);
  gemm_rows<4><<<625, 256, 0, stream>>>(x, WtS, b_self, xs);
  // CSR slot map (depends only on dst)
  hist_k<<<2500, 256, 0, stream>>>(dst, cnt, rank);
  scan_k<<<1, 1024, 0, stream>>>(cnt, ofs);
  pos_k<<<2500, 256, 0, stream>>>(dst, ofs, rank, pos);
  // edge transform: le (edge order) + w, m-pairs (CSR order)
  edge_kernel<<<10000, 256, 0, stream>>>(ea, WtE, b_edge, xm, att, src, pos,
                                         le_p, wcsr, mcsr);
  // pure-streaming per-node softmax + aggregation + self term
  node_agg<<<10000, 256, 0, stream>>>(mcsr, wcsr, xs, ofs, out_p);
}